// Round 3
// baseline (148.928 us; speedup 1.0000x reference)
//
#include <hip/hip_runtime.h>
#include <math.h>

#define T_STEPS 64
#define D_OUT 256
#define NCB 4   // nc per block; one wave per nc

typedef float vfloat4 __attribute__((ext_vector_type(4)));

// Block = 256 threads = 4 waves; wave w handles nc = nc_base + w.
// Lane jj owns 4 consecutive output channels j = 4*jj .. 4*jj+3,
// so each t-step stores one contiguous float4 (1 KB per wave per store).
// Delay/stochastic-rounding threshold computed in fp64 (matches the f64
// numpy reference on the noise<frac comparison), shared via LDS per block.
__global__ __launch_bounds__(256) void jeffress_kernel(
    const float* __restrict__ x,          // (T, NC, 2)
    const float* __restrict__ log_delay,  // (D_OUT)
    const float* __restrict__ log_weight, // (1)
    const float* __restrict__ noise,      // (NC, D_OUT, 2)
    float* __restrict__ out,              // (T, NC, D_OUT)
    int NC)
{
    __shared__ float  xs0[NCB][T_STEPS];
    __shared__ float  xs1[NCB][T_STEPS];
    __shared__ double fracd[D_OUT];
    __shared__ int    flo[D_OUT];
    __shared__ int    maxd[NCB][2];

    const int tid = threadIdx.x;
    const int nc_base = blockIdx.x * NCB;
    const int lnc = tid >> 6;   // wave id == local nc
    const int jj  = tid & 63;   // lane
    const int nc  = nc_base + lnc;

    // ---- stage x[:, nc_base..nc_base+3, :] into LDS (float2 per thread) ----
    {
        int t = tid >> 2;       // 0..63
        int l = tid & 3;        // local nc
        const float* xp = x + ((size_t)t * NC + nc_base + l) * 2;
        xs0[l][t] = xp[0];
        xs1[l][t] = xp[1];
    }
    // ---- per-j delay scaling: one fp64 exp per thread, once per block ----
    {
        double s = (double)T_STEPS * exp((double)log_delay[tid]);
        double f = floor(s);
        fracd[tid] = s - f;
        flo[tid]   = (int)f;
    }
    __syncthreads();

    // ---- argmax over time per (local nc, i); first-occurrence semantics ----
    if (tid < NCB * 2) {
        int l = tid >> 1, i = tid & 1;
        const float* xsrc = i ? xs1[l] : xs0[l];
        float best = xsrc[0]; int bi = 0;
        for (int t = 1; t < T_STEPS; ++t) {
            float v = xsrc[t];
            if (v > best) { best = v; bi = t; }
        }
        maxd[l][i] = (T_STEPS - 1) - bi;
    }
    __syncthreads();

    // ---- stochastic rounding + clamp for this thread's 8 channels ----
    // noise[(nc*D_OUT + 4*jj)*2 .. +7] = (j0,i0),(j0,i1),(j1,i0),(j1,i1),...
    const float* nptr = noise + ((size_t)nc * D_OUT + 4 * jj) * 2;
    float4 na = *(const float4*)(nptr);
    float4 nb = *(const float4*)(nptr + 4);
    float n0i[4] = { na.x, na.z, nb.x, nb.z };   // i=0 noise per c
    float n1i[4] = { na.y, na.w, nb.y, nb.w };   // i=1 noise per c

    const int md0 = maxd[lnc][0];
    const int md1 = maxd[lnc][1];

    int rd0[4], rd1[4];
    #pragma unroll
    for (int c = 0; c < 4; ++c) {
        int j  = 4 * jj + c;
        int jf = (D_OUT - 1) - j;
        int r0 = flo[j]  + (((double)n0i[c] < fracd[j])  ? 1 : 0);
        int r1 = flo[jf] + (((double)n1i[c] < fracd[jf]) ? 1 : 0);
        rd0[c] = min(r0, md0);
        rd1[c] = min(r1, md1);
    }

    const float w = (float)exp((double)log_weight[0]);

    // ---- leaky integrator (decay = 0.5 exact), float4 nontemporal stores ----
    float y0[4] = {0.f, 0.f, 0.f, 0.f};
    float y1[4] = {0.f, 0.f, 0.f, 0.f};
    const float* xr0 = xs0[lnc];
    const float* xr1 = xs1[lnc];
    float* op = out + ((size_t)nc) * D_OUT + 4 * jj;
    const size_t ostride = (size_t)NC * D_OUT;

    #pragma unroll
    for (int t = 0; t < T_STEPS; ++t) {
        vfloat4 o;
        #pragma unroll
        for (int c = 0; c < 4; ++c) {
            y0[c] = y0[c] * 0.5f + xr0[(t - rd0[c]) & (T_STEPS - 1)];
            y1[c] = y1[c] * 0.5f + xr1[(t - rd1[c]) & (T_STEPS - 1)];
            o[c] = (y0[c] + y1[c]) * w;
        }
        __builtin_nontemporal_store(o, (vfloat4*)(op + (size_t)t * ostride));
    }
}

extern "C" void kernel_launch(void* const* d_in, const int* in_sizes, int n_in,
                              void* d_out, int out_size, void* d_ws, size_t ws_size,
                              hipStream_t stream) {
    const float* x          = (const float*)d_in[0];
    const float* log_delay  = (const float*)d_in[1];
    const float* log_weight = (const float*)d_in[2];
    const float* noise      = (const float*)d_in[3];
    float* out = (float*)d_out;

    const int NC = in_sizes[3] / (D_OUT * 2);  // noise = (N,C,D_OUT,2)

    jeffress_kernel<<<NC / NCB, 256, 0, stream>>>(x, log_delay, log_weight, noise, out, NC);
}

// Round 4
// 148.220 us; speedup vs baseline: 1.0048x; 1.0048x over previous
//
#include <hip/hip_runtime.h>
#include <math.h>

#define T_STEPS 64
#define D_OUT 256

typedef float vfloat4 __attribute__((ext_vector_type(4)));

// One block per nc (grid=2048), 256 threads = 4 waves.
// All 4 waves run the 64-step leaky-integrator recurrence (decay=0.5 exact);
// wave w stores only t in [16w, 16w+16) -> 32 waves/CU issuing the write
// stream instead of 8. Lane jj owns channels j=4jj..4jj+3 (contiguous
// float4 store, plain/L2-routed -- NT hint removed, it never helped).
// Delay/stochastic-rounding threshold in fp64 to match the f64 numpy ref.
__global__ __launch_bounds__(256, 8) void jeffress_kernel(
    const float* __restrict__ x,          // (T, NC, 2)
    const float* __restrict__ log_delay,  // (D_OUT)
    const float* __restrict__ log_weight, // (1)
    const float* __restrict__ noise,      // (NC, D_OUT, 2)
    float* __restrict__ out,              // (T, NC, D_OUT)
    int NC)
{
    __shared__ float  xs0[T_STEPS];
    __shared__ float  xs1[T_STEPS];
    __shared__ double fracd[D_OUT];
    __shared__ int    flo[D_OUT];
    __shared__ int    maxd[2];

    const int tid = threadIdx.x;
    const int nc  = blockIdx.x;
    const int wv  = tid >> 6;   // wave id -> t-chunk
    const int jj  = tid & 63;   // lane -> channel group

    // ---- stage x[:, nc, :] into LDS ----
    if (tid < T_STEPS) {
        const float* xp = x + ((size_t)tid * NC + nc) * 2;
        xs0[tid] = xp[0];
        xs1[tid] = xp[1];
    }
    // ---- per-j delay scaling: fp64 exp, one channel per thread ----
    {
        double s = (double)T_STEPS * exp((double)log_delay[tid]);
        double f = floor(s);
        fracd[tid] = s - f;
        flo[tid]   = (int)f;
    }
    __syncthreads();

    // ---- argmax over time per side i (first occurrence -> strict '>') ----
    if (tid < 2) {
        const float* xsrc = tid ? xs1 : xs0;
        float best = xsrc[0]; int bi = 0;
        for (int t = 1; t < T_STEPS; ++t) {
            float v = xsrc[t];
            if (v > best) { best = v; bi = t; }
        }
        maxd[tid] = (T_STEPS - 1) - bi;
    }
    __syncthreads();

    // ---- stochastic rounding + clamp for this lane's 4 channels x 2 sides ----
    const float* nptr = noise + ((size_t)nc * D_OUT + 4 * jj) * 2;
    float4 na = *(const float4*)(nptr);
    float4 nb = *(const float4*)(nptr + 4);
    float n0i[4] = { na.x, na.z, nb.x, nb.z };   // i=0 noise per c
    float n1i[4] = { na.y, na.w, nb.y, nb.w };   // i=1 noise per c
    const int md0 = maxd[0], md1 = maxd[1];

    int rd0[4], rd1[4];
    #pragma unroll
    for (int c = 0; c < 4; ++c) {
        int j  = 4 * jj + c;
        int jf = (D_OUT - 1) - j;
        int r0 = flo[j]  + (((double)n0i[c] < fracd[j])  ? 1 : 0);
        int r1 = flo[jf] + (((double)n1i[c] < fracd[jf]) ? 1 : 0);
        rd0[c] = min(r0, md0);
        rd1[c] = min(r1, md1);
    }

    const float w = (float)exp((double)log_weight[0]);

    // ---- recurrence: warm-up (no stores) then 16 stored steps ----
    float y0[4] = {0.f, 0.f, 0.f, 0.f};
    float y1[4] = {0.f, 0.f, 0.f, 0.f};
    const int t0 = wv * 16;

    #pragma unroll 16
    for (int t = 0; t < t0; ++t) {
        #pragma unroll
        for (int c = 0; c < 4; ++c) {
            y0[c] = y0[c] * 0.5f + xs0[(t - rd0[c]) & (T_STEPS - 1)];
            y1[c] = y1[c] * 0.5f + xs1[(t - rd1[c]) & (T_STEPS - 1)];
        }
    }

    float* op = out + (size_t)nc * D_OUT + 4 * jj;
    const size_t ostride = (size_t)NC * D_OUT;
    #pragma unroll
    for (int k = 0; k < 16; ++k) {
        int t = t0 + k;
        vfloat4 o;
        #pragma unroll
        for (int c = 0; c < 4; ++c) {
            y0[c] = y0[c] * 0.5f + xs0[(t - rd0[c]) & (T_STEPS - 1)];
            y1[c] = y1[c] * 0.5f + xs1[(t - rd1[c]) & (T_STEPS - 1)];
            o[c] = (y0[c] + y1[c]) * w;
        }
        *(vfloat4*)(op + (size_t)t * ostride) = o;
    }
}

extern "C" void kernel_launch(void* const* d_in, const int* in_sizes, int n_in,
                              void* d_out, int out_size, void* d_ws, size_t ws_size,
                              hipStream_t stream) {
    const float* x          = (const float*)d_in[0];
    const float* log_delay  = (const float*)d_in[1];
    const float* log_weight = (const float*)d_in[2];
    const float* noise      = (const float*)d_in[3];
    float* out = (float*)d_out;

    const int NC = in_sizes[3] / (D_OUT * 2);  // noise = (N,C,D_OUT,2)

    jeffress_kernel<<<NC, 256, 0, stream>>>(x, log_delay, log_weight, noise, out, NC);
}